// Round 3
// baseline (730.892 us; speedup 1.0000x reference)
//
#include <hip/hip_runtime.h>
#include <hip/hip_bf16.h>

#define NUM_U 100000
#define NUM_I 100000
#define NE    1600000
#define NL    100000
#define CAP   48
#define NBIN  391        // ceil(100000/256) coarse bins (dst>>8)
#define BINCAP 4608      // per-bin capacity; E[bin]=4096, +8 sigma
#define ROUND  4096      // edges per partition block
#define PB    391        // partition blocks per edge type = ceil(NE/ROUND)
#define FM    64         // output rows per fused block

typedef __attribute__((ext_vector_type(4))) float floatx4;
typedef __attribute__((ext_vector_type(8))) short shortx8;
typedef unsigned long long u64;

__device__ __forceinline__ float bf_lo(unsigned v) { return __uint_as_float(v << 16); }
__device__ __forceinline__ float bf_hi(unsigned v) { return __uint_as_float(v & 0xffff0000u); }

__device__ __forceinline__ unsigned pack_bf16x2(float lo, float hi) {
    __hip_bfloat16 l = __float2bfloat16(lo);
    __hip_bfloat16 h = __float2bfloat16(hi);
    unsigned short ul = *(unsigned short*)&l;
    unsigned short uh = *(unsigned short*)&h;
    return (unsigned)ul | ((unsigned)uh << 16);
}

__device__ __forceinline__ int clampi(int x, int hi) {
    return min(max(x, 0), hi - 1);
}

// -------- zero f32 tail of d_out beyond NL (poisoned 0xAA otherwise)
__global__ void zero_f32_kernel(float* __restrict__ p, int n) {
    int i = blockIdx.x * blockDim.x + threadIdx.x;
    if (i < n) p[i] = 0.0f;
}

// -------- both emb tables f32 [N][128] -> packed bf16x2, one dispatch
__global__ void conv2_kernel(const float* __restrict__ emb_u, const float* __restrict__ emb_i,
                             unsigned* __restrict__ xu, unsigned* __restrict__ xi) {
    int i = blockIdx.x * blockDim.x + threadIdx.x;
    const int nu = NUM_U * 64;
    if (i < nu) {
        float2 v = ((const float2*)emb_u)[i];
        xu[i] = pack_bf16x2(v.x, v.y);
    } else if (i < nu + NUM_I * 64) {
        int j = i - nu;
        float2 v = ((const float2*)emb_i)[j];
        xi[j] = pack_bf16x2(v.x, v.y);
    }
}

// -------- transpose the 4 f32 weight pairs into bf16 Bt[which][n][k]; also zeros bin_cursor
__global__ void transpose_w4_kernel(
    const float* __restrict__ w1l_rates, const float* __restrict__ w1r_rates,
    const float* __restrict__ w1l_rev,   const float* __restrict__ w1r_rev,
    const float* __restrict__ w2l_rates, const float* __restrict__ w2r_rates,
    const float* __restrict__ w2l_rev,   const float* __restrict__ w2r_rev,
    short* __restrict__ Bt, int* __restrict__ bin_cursor) {
    int idx = blockIdx.x * blockDim.x + threadIdx.x;  // 0 .. 4*32768-1
    if (idx < 2 * NBIN) bin_cursor[idx] = 0;
    int which = idx >> 15;
    int r = idx & 32767;
    int n = r >> 8;
    int k = r & 255;
    const float *wl, *wr;
    switch (which) {
        case 0:  wl = w1l_rates; wr = w1r_rates; break;
        case 1:  wl = w1l_rev;   wr = w1r_rev;   break;
        case 2:  wl = w2l_rates; wr = w2r_rates; break;
        default: wl = w2l_rev;   wr = w2r_rev;   break;
    }
    float v = (k < 128) ? wl[k * 128 + n] : wr[(k - 128) * 128 + n];
    __hip_bfloat16 b = __float2bfloat16(v);
    Bt[idx] = *(const short*)&b;
}

// -------- phase P (both edge types): block-local counting sort by dst>>8, coalesced
// runs into per-bin regions. bin_data entry = dst<<32|src.
__global__ __launch_bounds__(256) void partition2_kernel(
    const int* __restrict__ edges0, const int* __restrict__ edges1,
    u64* __restrict__ bd0, u64* __restrict__ bd1, int* __restrict__ cur) {
    __shared__ int hist[NBIN];
    __shared__ int prefix[NBIN];
    __shared__ int gbase[NBIN];
    __shared__ __align__(16) u64 sorted[ROUND];

    const int type = (blockIdx.x >= PB) ? 1 : 0;
    const int* edges = type ? edges1 : edges0;
    u64* bin_data = type ? bd1 : bd0;
    int* bin_cursor = cur + type * NBIN;
    const int blk  = blockIdx.x - type * PB;
    const int tid  = threadIdx.x;
    const int lane = tid & 63;
    const int wv   = tid >> 6;
    const int base = blk * ROUND;

    for (int k = tid; k < NBIN; k += 256) hist[k] = 0;
    __syncthreads();

    int mybin[16], myrank[16], mysrc[16], mydst[16];
#pragma unroll
    for (int r = 0; r < 16; r++) {
        int i = base + r * 256 + tid;
        mybin[r] = -1;
        if (i < NE) {
            mysrc[r] = clampi(edges[i], NUM_U);
            mydst[r] = clampi(edges[i + NE], NUM_I);
            mybin[r] = mydst[r] >> 8;
            myrank[r] = atomicAdd(&hist[mybin[r]], 1);
        }
    }
    __syncthreads();

    if (wv == 0) {   // exclusive scan of hist -> prefix
        int carry = 0;
        for (int c = 0; c < NBIN; c += 64) {
            int idx = c + lane;
            int h = (idx < NBIN) ? hist[idx] : 0;
            int v = h;
            for (int o = 1; o < 64; o <<= 1) {
                int t = __shfl_up(v, o);
                if (lane >= o) v += t;
            }
            if (idx < NBIN) prefix[idx] = v - h + carry;
            carry += __shfl(v, 63);
        }
    }
    __syncthreads();

#pragma unroll
    for (int r = 0; r < 16; r++) {
        if (mybin[r] >= 0) {
            int j = prefix[mybin[r]] + myrank[r];
            sorted[j] = ((u64)(unsigned)mydst[r] << 32) | (unsigned)mysrc[r];
        }
    }
    __syncthreads();

    for (int b = tid; b < NBIN; b += 256) {
        int cnt = hist[b];
        gbase[b] = (cnt > 0) ? atomicAdd(&bin_cursor[b], cnt) : 0;
    }
    __syncthreads();

    int total = min(ROUND, NE - base);
    for (int j = tid; j < total; j += 256) {
        u64 e = sorted[j];
        int b = (int)(e >> 40);
        int pos = gbase[b] + (j - prefix[b]);
        if (pos < BINCAP)
            bin_data[(size_t)b * BINCAP + pos] = e;
    }
}

// -------- phase Q (both edge types): one block per bin; LDS bucket build, coalesced out
__global__ __launch_bounds__(256) void binscatter2_kernel(
    const u64* __restrict__ bd0, const u64* __restrict__ bd1, const int* __restrict__ cur,
    int* __restrict__ deg0, int* __restrict__ bucket0,
    int* __restrict__ deg1, int* __restrict__ bucket1) {
    __shared__ int lbucket[256 * CAP];   // 48 KB
    __shared__ int ldeg[256];
    const int type = (blockIdx.x >= NBIN) ? 1 : 0;
    const int b = blockIdx.x - type * NBIN;
    const u64* bin_data = type ? bd1 : bd0;
    int* deg = type ? deg1 : deg0;
    int* bucket = type ? bucket1 : bucket0;
    const int tid = threadIdx.x;
    const int dstbase = b << 8;
    const int n_dst = NUM_I;

    ldeg[tid] = 0;
    __syncthreads();

    int count = min(cur[type * NBIN + b], BINCAP);
    for (int j = tid; j < count; j += 256) {
        u64 e = bin_data[(size_t)b * BINCAP + j];
        int src = (int)(unsigned)e;
        int dl = ((int)(e >> 32)) & 255;
        int pos = atomicAdd(&ldeg[dl], 1);
        if (pos < CAP) lbucket[dl * CAP + pos] = src;
    }
    __syncthreads();

    if (dstbase + tid < n_dst) deg[dstbase + tid] = ldeg[tid];
    int limit = min(256, n_dst - dstbase) * CAP;
    for (int k = tid; k < limit; k += 256)
        bucket[(size_t)dstbase * CAP + k] = lbucket[k];
}

// -------- FUSED aggregation + GEMM + normalize + relu, both node types.
// One block = FM(64) output rows. Phase 1: each of 4 waves gather-means 16 rows
// (deg preloaded once, bucket row i+1 prefetched under row i's gathers; 8-deep
// gather ILP), packing bf16 means directly into LDS in MFMA layout. Phase 2:
// 64x128x256 MFMA GEMM [mean|x_dst]@[wl;wr]+b; the x_dst A-fragments are loaded
// straight from global into registers (no LDS staging -> 17.9 KB LDS total for
// gather-phase occupancy), issued in one batch so latency hides under the
// mean-half MFMAs. Then row-normalize, relu, pack bf16 -> out (ping-pong buffer).
__global__ __launch_bounds__(256) void fused_kernel(
    const int* __restrict__ degA, const int* __restrict__ bucketA,
    const unsigned* __restrict__ xsA, const unsigned* __restrict__ xdA,
    const short* __restrict__ BtA, const float* __restrict__ biasA,
    unsigned* __restrict__ outA,
    const int* __restrict__ degB, const int* __restrict__ bucketB,
    const unsigned* __restrict__ xsB, const unsigned* __restrict__ xdB,
    const short* __restrict__ BtB, const float* __restrict__ biasB,
    unsigned* __restrict__ outB, int nblocksA) {
    __shared__ unsigned mean_lds[FM][68];          // bf16x2-packed mean rows, 17.4 KB
    __shared__ float rowsum[FM][2];

    const int half = (blockIdx.x >= nblocksA) ? 1 : 0;
    const int* deg = half ? degB : degA;
    const int* bucket = half ? bucketB : bucketA;
    const unsigned* xsrc = half ? xsB : xsA;
    const unsigned* xdst = half ? xdB : xdA;
    const short* Bt = half ? BtB : BtA;
    const float* bias = half ? biasB : biasA;
    unsigned* outb = half ? outB : outA;
    const int rb = (blockIdx.x - half * nblocksA) * FM;
    const int n_rows = NUM_I;   // == NUM_U

    const int tid  = threadIdx.x;
    const int lane = tid & 63;
    const int wv   = tid >> 6;
    const int wm   = wv >> 1;
    const int wn   = wv & 1;
    const int l15  = lane & 15;
    const int lq   = lane >> 4;

    // ---- phase 1: gather + mean for this wave's 16 rows
    {
        const int r0 = rb + wv * 16;
        int dv = 0;
        if (lane < 16 && r0 + lane < n_rows)
            dv = __builtin_nontemporal_load(&deg[r0 + lane]);
        int srcs = 0;
        if (r0 < n_rows && lane < CAP)
            srcs = __builtin_nontemporal_load(&bucket[(size_t)r0 * CAP + lane]);
        for (int i = 0; i < 16; i++) {
            const int row = r0 + i;
            int srcs_next = 0;
            if (i < 15 && row + 1 < n_rows && lane < CAP)
                srcs_next = __builtin_nontemporal_load(&bucket[(size_t)(row + 1) * CAP + lane]);
            int d = __builtin_amdgcn_readlane(dv, i);
            int cnt = (row < n_rows) ? min(d, CAP) : 0;
            float a0 = 0.f, a1 = 0.f;
            int e = 0;
            for (; e + 8 <= cnt; e += 8) {
                int s0 = __builtin_amdgcn_readlane(srcs, e + 0);
                int s1 = __builtin_amdgcn_readlane(srcs, e + 1);
                int s2 = __builtin_amdgcn_readlane(srcs, e + 2);
                int s3 = __builtin_amdgcn_readlane(srcs, e + 3);
                int s4 = __builtin_amdgcn_readlane(srcs, e + 4);
                int s5 = __builtin_amdgcn_readlane(srcs, e + 5);
                int s6 = __builtin_amdgcn_readlane(srcs, e + 6);
                int s7 = __builtin_amdgcn_readlane(srcs, e + 7);
                unsigned v0 = xsrc[(size_t)s0 * 64 + lane];
                unsigned v1 = xsrc[(size_t)s1 * 64 + lane];
                unsigned v2 = xsrc[(size_t)s2 * 64 + lane];
                unsigned v3 = xsrc[(size_t)s3 * 64 + lane];
                unsigned v4 = xsrc[(size_t)s4 * 64 + lane];
                unsigned v5 = xsrc[(size_t)s5 * 64 + lane];
                unsigned v6 = xsrc[(size_t)s6 * 64 + lane];
                unsigned v7 = xsrc[(size_t)s7 * 64 + lane];
                a0 += bf_lo(v0) + bf_lo(v1) + bf_lo(v2) + bf_lo(v3)
                    + bf_lo(v4) + bf_lo(v5) + bf_lo(v6) + bf_lo(v7);
                a1 += bf_hi(v0) + bf_hi(v1) + bf_hi(v2) + bf_hi(v3)
                    + bf_hi(v4) + bf_hi(v5) + bf_hi(v6) + bf_hi(v7);
            }
            for (; e + 4 <= cnt; e += 4) {
                int s0 = __builtin_amdgcn_readlane(srcs, e + 0);
                int s1 = __builtin_amdgcn_readlane(srcs, e + 1);
                int s2 = __builtin_amdgcn_readlane(srcs, e + 2);
                int s3 = __builtin_amdgcn_readlane(srcs, e + 3);
                unsigned v0 = xsrc[(size_t)s0 * 64 + lane];
                unsigned v1 = xsrc[(size_t)s1 * 64 + lane];
                unsigned v2 = xsrc[(size_t)s2 * 64 + lane];
                unsigned v3 = xsrc[(size_t)s3 * 64 + lane];
                a0 += bf_lo(v0) + bf_lo(v1) + bf_lo(v2) + bf_lo(v3);
                a1 += bf_hi(v0) + bf_hi(v1) + bf_hi(v2) + bf_hi(v3);
            }
            for (; e < cnt; e++) {
                int s0 = __builtin_amdgcn_readlane(srcs, e);
                unsigned v0 = xsrc[(size_t)s0 * 64 + lane];
                a0 += bf_lo(v0); a1 += bf_hi(v0);
            }
            float scale = 1.0f / (float)max(d, 1);
            if (row < n_rows)
                mean_lds[row - rb][lane] = pack_bf16x2(a0 * scale, a1 * scale);
            srcs = srcs_next;
        }
    }

    // ---- phase 2: GEMM
    floatx4 acc[2][4];
#pragma unroll
    for (int nt = 0; nt < 4; nt++) {
        float b = bias[wn * 64 + nt * 16 + l15];
#pragma unroll
        for (int mt = 0; mt < 2; mt++) acc[mt][nt] = (floatx4){b, b, b, b};
    }

    __syncthreads();   // mean_lds ready

    // issue all 8 x_dst A-fragments (kt=2,3 half) from global now; latency hides
    // under the mean-half MFMAs below. Each lane reads 16B of its own row.
    uint4 axd[2][2][2];   // [ktr][kk2][mt]
#pragma unroll
    for (int ktr = 0; ktr < 2; ktr++)
#pragma unroll
        for (int kk2 = 0; kk2 < 2; kk2++)
#pragma unroll
            for (int mt = 0; mt < 2; mt++) {
                int row_l = wm * 32 + mt * 16 + l15;
                int grow = rb + row_l;
                uint4 v = make_uint4(0u, 0u, 0u, 0u);
                if (grow < n_rows)
                    v = *(const uint4*)(xdst + (size_t)grow * 64 + ktr * 32 + kk2 * 16 + lq * 4);
                axd[ktr][kk2][mt] = v;
            }

    // kt = 0,1: A-operand from mean_lds (K = 0..127, the mean @ wl half)
#pragma unroll
    for (int kt = 0; kt < 2; kt++) {
#pragma unroll
        for (int kk = 0; kk < 64; kk += 32) {
            shortx8 af[2], bfr[4];
#pragma unroll
            for (int mt = 0; mt < 2; mt++) {
                int row_l = wm * 32 + mt * 16 + l15;
                af[mt] = *(const shortx8*)&mean_lds[row_l][kt * 32 + (kk >> 1) + lq * 4];
            }
#pragma unroll
            for (int nt = 0; nt < 4; nt++) {
                int col = wn * 64 + nt * 16 + l15;
                int kg = kt * 64 + kk + lq * 8;
                bfr[nt] = *(const shortx8*)(Bt + col * 256 + kg);
            }
#pragma unroll
            for (int mt = 0; mt < 2; mt++)
#pragma unroll
                for (int nt = 0; nt < 4; nt++)
                    acc[mt][nt] = __builtin_amdgcn_mfma_f32_16x16x32_bf16(
                        af[mt], bfr[nt], acc[mt][nt], 0, 0, 0);
        }
    }

    // kt = 2,3: A-operand from the preloaded x_dst registers (the x @ wr half)
#pragma unroll
    for (int ktr = 0; ktr < 2; ktr++) {
#pragma unroll
        for (int kk2 = 0; kk2 < 2; kk2++) {
            shortx8 af[2], bfr[4];
#pragma unroll
            for (int mt = 0; mt < 2; mt++)
                af[mt] = *(const shortx8*)&axd[ktr][kk2][mt];
#pragma unroll
            for (int nt = 0; nt < 4; nt++) {
                int col = wn * 64 + nt * 16 + l15;
                int kg = (2 + ktr) * 64 + kk2 * 32 + lq * 8;
                bfr[nt] = *(const shortx8*)(Bt + col * 256 + kg);
            }
#pragma unroll
            for (int mt = 0; mt < 2; mt++)
#pragma unroll
                for (int nt = 0; nt < 4; nt++)
                    acc[mt][nt] = __builtin_amdgcn_mfma_f32_16x16x32_bf16(
                        af[mt], bfr[nt], acc[mt][nt], 0, 0, 0);
        }
    }

    // ---- normalize + relu + pack out
#pragma unroll
    for (int mt = 0; mt < 2; mt++) {
#pragma unroll
        for (int r = 0; r < 4; r++) {
            float p = 0.f;
#pragma unroll
            for (int nt = 0; nt < 4; nt++) { float x = acc[mt][nt][r]; p += x * x; }
            for (int o = 1; o < 16; o <<= 1) p += __shfl_xor(p, o);
            if (l15 == 0) rowsum[wm * 32 + mt * 16 + lq * 4 + r][wn] = p;
        }
    }
    __syncthreads();

#pragma unroll
    for (int mt = 0; mt < 2; mt++) {
#pragma unroll
        for (int r = 0; r < 4; r++) {
            int row_l = wm * 32 + mt * 16 + lq * 4 + r;
            int grow = rb + row_l;
            float s = rowsum[row_l][0] + rowsum[row_l][1];
            float inv = 1.f / fmaxf(sqrtf(s), 1e-12f);
#pragma unroll
            for (int nt = 0; nt < 4; nt++) {
                float v = fmaxf(acc[mt][nt][r] * inv, 0.f);
                float vnb = __shfl_xor(v, 1);
                if (grow < n_rows && (l15 & 1) == 0) {
                    int colpair = (wn * 64 + nt * 16 + l15) >> 1;
                    __builtin_nontemporal_store(pack_bf16x2(v, vnb),
                                                &outb[(size_t)grow * 64 + colpair]);
                }
            }
        }
    }
}

// -------- classifier: dot(xu2[src], xi2[dst]) per labeled edge, one wave per pair
__global__ __launch_bounds__(256) void classifier_kernel(
    const unsigned* __restrict__ xu, const unsigned* __restrict__ xi,
    const int* __restrict__ eli, float* __restrict__ out, int nL) {
    int wave = (blockIdx.x * blockDim.x + threadIdx.x) >> 6;
    int lane = threadIdx.x & 63;
    if (wave >= nL) return;
    int su = clampi(eli[wave], NUM_U);
    int di = clampi(eli[wave + nL], NUM_I);
    unsigned a = xu[(size_t)su * 64 + lane];
    unsigned b = xi[(size_t)di * 64 + lane];
    float p = bf_lo(a) * bf_lo(b) + bf_hi(a) * bf_hi(b);
    for (int o = 32; o; o >>= 1) p += __shfl_xor(p, o);
    if (lane == 0) __builtin_nontemporal_store(p, &out[wave]);
}

extern "C" void kernel_launch(void* const* d_in, const int* in_sizes, int n_in,
                              void* d_out, int out_size, void* d_ws, size_t ws_size,
                              hipStream_t stream) {
    const float* emb_user = (const float*)d_in[0];
    const float* emb_item = (const float*)d_in[1];
    const int* edge_rates = (const int*)d_in[2];
    const int* edge_rev   = (const int*)d_in[3];
    const int* eli        = (const int*)d_in[4];
    const float* b1_rates = (const float*)d_in[13];
    const float* b1_rev   = (const float*)d_in[14];
    const float* b2_rates = (const float*)d_in[15];
    const float* b2_rev   = (const float*)d_in[16];

    // workspace layout — ~136 MiB (bin_data regions alias xi1/xu1, dead until fused L1)
    char* p = (char*)d_ws;
    auto alloc = [&](size_t bytes) -> void* {
        void* q = (void*)p;
        p += (bytes + 511) & ~(size_t)511;
        return q;
    };
    int* deg_rates    = (int*)alloc((size_t)NUM_I * 4);
    int* bucket_rates = (int*)alloc((size_t)NUM_I * CAP * 4);
    int* deg_rev      = (int*)alloc((size_t)NUM_U * 4);
    int* bucket_rev   = (int*)alloc((size_t)NUM_U * CAP * 4);
    unsigned* xi0 = (unsigned*)alloc((size_t)NUM_I * 64 * 4);   // embI bf16; later xi2
    unsigned* xu0 = (unsigned*)alloc((size_t)NUM_U * 64 * 4);   // embU bf16; later xu2
    unsigned* xi1 = (unsigned*)alloc((size_t)NUM_I * 64 * 4);
    unsigned* xu1 = (unsigned*)alloc((size_t)NUM_U * 64 * 4);
    short* Bt = (short*)alloc((size_t)4 * 32768 * 2);
    int* bin_cursor = (int*)alloc((size_t)2 * NBIN * 4);
    u64* bd0 = (u64*)xi1;   // 391*4608*8 = 14.4 MB <= 25.6 MB, dead before fused L1 writes
    u64* bd1 = (u64*)xu1;

    const int fmBlocks = (NUM_I + FM - 1) / FM;                  // 1563
    const int conv2Blocks = ((NUM_U + NUM_I) * 64 + 255) / 256;

    if (out_size > NL) {
        int tail = out_size - NL;
        zero_f32_kernel<<<(tail + 255) / 256, 256, 0, stream>>>((float*)d_out + NL, tail);
    }

    // ---- one-time prep
    transpose_w4_kernel<<<512, 256, 0, stream>>>(
        (const float*)d_in[5], (const float*)d_in[6],
        (const float*)d_in[7], (const float*)d_in[8],
        (const float*)d_in[9], (const float*)d_in[10],
        (const float*)d_in[11], (const float*)d_in[12], Bt, bin_cursor);
    conv2_kernel<<<conv2Blocks, 256, 0, stream>>>(emb_user, emb_item, xu0, xi0);
    partition2_kernel<<<2 * PB, 256, 0, stream>>>(edge_rates, edge_rev, bd0, bd1, bin_cursor);
    binscatter2_kernel<<<2 * NBIN, 256, 0, stream>>>(bd0, bd1, bin_cursor,
                                                     deg_rates, bucket_rates,
                                                     deg_rev, bucket_rev);

    // ---- layer 1: x0 -> x1 (item side gathers xu0, user side gathers xi0)
    fused_kernel<<<2 * fmBlocks, 256, 0, stream>>>(
        deg_rates, bucket_rates, xu0, xi0, Bt + 0 * 32768, b1_rates, xi1,
        deg_rev,   bucket_rev,   xi0, xu0, Bt + 1 * 32768, b1_rev,   xu1,
        fmBlocks);

    // ---- layer 2: x1 -> x2 (reusing x0 buffers)
    fused_kernel<<<2 * fmBlocks, 256, 0, stream>>>(
        deg_rates, bucket_rates, xu1, xi1, Bt + 2 * 32768, b2_rates, xi0,
        deg_rev,   bucket_rev,   xi1, xu1, Bt + 3 * 32768, b2_rev,   xu0,
        fmBlocks);

    classifier_kernel<<<(NL * 64 + 255) / 256, 256, 0, stream>>>(xu0, xi0, eli,
                                                                 (float*)d_out, NL);
}

// Round 4
// 631.556 us; speedup vs baseline: 1.1573x; 1.1573x over previous
//
#include <hip/hip_runtime.h>
#include <hip/hip_bf16.h>

#define NUM_U 100000
#define NUM_I 100000
#define NE    1600000
#define NL    100000
#define CAP   48
#define NBIN  391        // ceil(100000/256) coarse bins (dst>>8)
#define BINCAP 4608      // per-bin capacity; E[bin]=4096, +8 sigma
#define ROUND  4096      // edges per partition block
#define PB    391        // partition blocks per edge type = ceil(NE/ROUND)

typedef __attribute__((ext_vector_type(4))) float floatx4;
typedef __attribute__((ext_vector_type(8))) short shortx8;
typedef unsigned long long u64;

__device__ __forceinline__ float bf_lo(unsigned v) { return __uint_as_float(v << 16); }
__device__ __forceinline__ float bf_hi(unsigned v) { return __uint_as_float(v & 0xffff0000u); }

__device__ __forceinline__ unsigned pack_bf16x2(float lo, float hi) {
    __hip_bfloat16 l = __float2bfloat16(lo);
    __hip_bfloat16 h = __float2bfloat16(hi);
    unsigned short ul = *(unsigned short*)&l;
    unsigned short uh = *(unsigned short*)&h;
    return (unsigned)ul | ((unsigned)uh << 16);
}

__device__ __forceinline__ int clampi(int x, int hi) {
    return min(max(x, 0), hi - 1);
}

// -------- zero f32 tail of d_out beyond NL (poisoned 0xAA otherwise)
__global__ void zero_f32_kernel(float* __restrict__ p, int n) {
    int i = blockIdx.x * blockDim.x + threadIdx.x;
    if (i < n) p[i] = 0.0f;
}

// -------- both emb tables f32 [N][128] -> packed bf16x2, one dispatch
__global__ void conv2_kernel(const float* __restrict__ emb_u, const float* __restrict__ emb_i,
                             unsigned* __restrict__ xu, unsigned* __restrict__ xi) {
    int i = blockIdx.x * blockDim.x + threadIdx.x;
    const int nu = NUM_U * 64;
    if (i < nu) {
        float2 v = ((const float2*)emb_u)[i];
        xu[i] = pack_bf16x2(v.x, v.y);
    } else if (i < nu + NUM_I * 64) {
        int j = i - nu;
        float2 v = ((const float2*)emb_i)[j];
        xi[j] = pack_bf16x2(v.x, v.y);
    }
}

// -------- transpose the 4 f32 weight pairs into bf16 Bt[which][n][k]; also zeros bin_cursor
__global__ void transpose_w4_kernel(
    const float* __restrict__ w1l_rates, const float* __restrict__ w1r_rates,
    const float* __restrict__ w1l_rev,   const float* __restrict__ w1r_rev,
    const float* __restrict__ w2l_rates, const float* __restrict__ w2r_rates,
    const float* __restrict__ w2l_rev,   const float* __restrict__ w2r_rev,
    short* __restrict__ Bt, int* __restrict__ bin_cursor) {
    int idx = blockIdx.x * blockDim.x + threadIdx.x;  // 0 .. 4*32768-1
    if (idx < 2 * NBIN) bin_cursor[idx] = 0;
    int which = idx >> 15;
    int r = idx & 32767;
    int n = r >> 8;
    int k = r & 255;
    const float *wl, *wr;
    switch (which) {
        case 0:  wl = w1l_rates; wr = w1r_rates; break;
        case 1:  wl = w1l_rev;   wr = w1r_rev;   break;
        case 2:  wl = w2l_rates; wr = w2r_rates; break;
        default: wl = w2l_rev;   wr = w2r_rev;   break;
    }
    float v = (k < 128) ? wl[k * 128 + n] : wr[(k - 128) * 128 + n];
    __hip_bfloat16 b = __float2bfloat16(v);
    Bt[idx] = *(const short*)&b;
}

// -------- phase P (both edge types): block-local counting sort by dst>>8, coalesced
// runs into per-bin regions. bin_data entry = dst<<32|src.
__global__ __launch_bounds__(256) void partition2_kernel(
    const int* __restrict__ edges0, const int* __restrict__ edges1,
    u64* __restrict__ bd0, u64* __restrict__ bd1, int* __restrict__ cur) {
    __shared__ int hist[NBIN];
    __shared__ int prefix[NBIN];
    __shared__ int gbase[NBIN];
    __shared__ __align__(16) u64 sorted[ROUND];

    const int type = (blockIdx.x >= PB) ? 1 : 0;
    const int* edges = type ? edges1 : edges0;
    u64* bin_data = type ? bd1 : bd0;
    int* bin_cursor = cur + type * NBIN;
    const int blk  = blockIdx.x - type * PB;
    const int tid  = threadIdx.x;
    const int lane = tid & 63;
    const int wv   = tid >> 6;
    const int base = blk * ROUND;

    for (int k = tid; k < NBIN; k += 256) hist[k] = 0;
    __syncthreads();

    int mybin[16], myrank[16], mysrc[16], mydst[16];
#pragma unroll
    for (int r = 0; r < 16; r++) {
        int i = base + r * 256 + tid;
        mybin[r] = -1;
        if (i < NE) {
            mysrc[r] = clampi(edges[i], NUM_U);
            mydst[r] = clampi(edges[i + NE], NUM_I);
            mybin[r] = mydst[r] >> 8;
            myrank[r] = atomicAdd(&hist[mybin[r]], 1);
        }
    }
    __syncthreads();

    if (wv == 0) {   // exclusive scan of hist -> prefix
        int carry = 0;
        for (int c = 0; c < NBIN; c += 64) {
            int idx = c + lane;
            int h = (idx < NBIN) ? hist[idx] : 0;
            int v = h;
            for (int o = 1; o < 64; o <<= 1) {
                int t = __shfl_up(v, o);
                if (lane >= o) v += t;
            }
            if (idx < NBIN) prefix[idx] = v - h + carry;
            carry += __shfl(v, 63);
        }
    }
    __syncthreads();

#pragma unroll
    for (int r = 0; r < 16; r++) {
        if (mybin[r] >= 0) {
            int j = prefix[mybin[r]] + myrank[r];
            sorted[j] = ((u64)(unsigned)mydst[r] << 32) | (unsigned)mysrc[r];
        }
    }
    __syncthreads();

    for (int b = tid; b < NBIN; b += 256) {
        int cnt = hist[b];
        gbase[b] = (cnt > 0) ? atomicAdd(&bin_cursor[b], cnt) : 0;
    }
    __syncthreads();

    int total = min(ROUND, NE - base);
    for (int j = tid; j < total; j += 256) {
        u64 e = sorted[j];
        int b = (int)(e >> 40);
        int pos = gbase[b] + (j - prefix[b]);
        if (pos < BINCAP)
            bin_data[(size_t)b * BINCAP + pos] = e;
    }
}

// -------- phase Q (both edge types): one block per bin; LDS bucket build, coalesced out
__global__ __launch_bounds__(256) void binscatter2_kernel(
    const u64* __restrict__ bd0, const u64* __restrict__ bd1, const int* __restrict__ cur,
    int* __restrict__ deg0, int* __restrict__ bucket0,
    int* __restrict__ deg1, int* __restrict__ bucket1) {
    __shared__ int lbucket[256 * CAP];   // 48 KB
    __shared__ int ldeg[256];
    const int type = (blockIdx.x >= NBIN) ? 1 : 0;
    const int b = blockIdx.x - type * NBIN;
    const u64* bin_data = type ? bd1 : bd0;
    int* deg = type ? deg1 : deg0;
    int* bucket = type ? bucket1 : bucket0;
    const int tid = threadIdx.x;
    const int dstbase = b << 8;
    const int n_dst = NUM_I;

    ldeg[tid] = 0;
    __syncthreads();

    int count = min(cur[type * NBIN + b], BINCAP);
    for (int j = tid; j < count; j += 256) {
        u64 e = bin_data[(size_t)b * BINCAP + j];
        int src = (int)(unsigned)e;
        int dl = ((int)(e >> 32)) & 255;
        int pos = atomicAdd(&ldeg[dl], 1);
        if (pos < CAP) lbucket[dl * CAP + pos] = src;
    }
    __syncthreads();

    if (dstbase + tid < n_dst) deg[dstbase + tid] = ldeg[tid];
    int limit = min(256, n_dst - dstbase) * CAP;
    for (int k = tid; k < limit; k += 256)
        bucket[(size_t)dstbase * CAP + k] = lbucket[k];
}

// -------- merged aggregation (both edge types), XCD-partitioned: blocks whose
// bid%8 is in {0..3} handle type A (items, gather xu); {4..7} handle type B
// (users, gather xi). Each 25.6 MB gather table then lives in one 4-XCD L2
// group (16 MB) instead of being duplicated into all 8 XCD L2s — targets the
// L2-fill path, which the counters identify as the binding resource.
// One wave per dst node; readlane broadcasts (wave-uniform counter) keep src
// row bases in SGPRs; deg/bucket reads and mean stores are nontemporal.
__global__ __launch_bounds__(256) void agg2_kernel(
    const int* __restrict__ degA, const int* __restrict__ bucketA,
    const unsigned* __restrict__ xA, unsigned* __restrict__ outA,
    const int* __restrict__ degB, const int* __restrict__ bucketB,
    const unsigned* __restrict__ xB, unsigned* __restrict__ outB) {
    const int bid = blockIdx.x;
    const int xcd = bid & 7;
    const int typeB = (xcd >= 4);
    const int gidx = (bid >> 3) * 4 + (xcd & 3);   // 0..24999 per type
    const int node = gidx * 4 + (threadIdx.x >> 6);
    const int lane = threadIdx.x & 63;
    if (node >= NUM_I) return;   // NUM_I == NUM_U

    const int* deg; const int* bucket; const unsigned* xb; unsigned* mo;
    if (!typeB) { deg = degA; bucket = bucketA; xb = xA; mo = outA; }
    else        { deg = degB; bucket = bucketB; xb = xB; mo = outB; }

    int d = __builtin_nontemporal_load(&deg[node]);
    int cnt = min(d, CAP);
    int srcs = (lane < cnt) ? __builtin_nontemporal_load(&bucket[(size_t)node * CAP + lane]) : 0;
    float a0 = 0.f, a1 = 0.f;
    int e = 0;
    for (; e + 8 <= cnt; e += 8) {
        int s0 = __builtin_amdgcn_readlane(srcs, e + 0);
        int s1 = __builtin_amdgcn_readlane(srcs, e + 1);
        int s2 = __builtin_amdgcn_readlane(srcs, e + 2);
        int s3 = __builtin_amdgcn_readlane(srcs, e + 3);
        int s4 = __builtin_amdgcn_readlane(srcs, e + 4);
        int s5 = __builtin_amdgcn_readlane(srcs, e + 5);
        int s6 = __builtin_amdgcn_readlane(srcs, e + 6);
        int s7 = __builtin_amdgcn_readlane(srcs, e + 7);
        unsigned v0 = xb[(size_t)s0 * 64 + lane];
        unsigned v1 = xb[(size_t)s1 * 64 + lane];
        unsigned v2 = xb[(size_t)s2 * 64 + lane];
        unsigned v3 = xb[(size_t)s3 * 64 + lane];
        unsigned v4 = xb[(size_t)s4 * 64 + lane];
        unsigned v5 = xb[(size_t)s5 * 64 + lane];
        unsigned v6 = xb[(size_t)s6 * 64 + lane];
        unsigned v7 = xb[(size_t)s7 * 64 + lane];
        a0 += bf_lo(v0) + bf_lo(v1) + bf_lo(v2) + bf_lo(v3)
            + bf_lo(v4) + bf_lo(v5) + bf_lo(v6) + bf_lo(v7);
        a1 += bf_hi(v0) + bf_hi(v1) + bf_hi(v2) + bf_hi(v3)
            + bf_hi(v4) + bf_hi(v5) + bf_hi(v6) + bf_hi(v7);
    }
    for (; e + 4 <= cnt; e += 4) {
        int s0 = __builtin_amdgcn_readlane(srcs, e + 0);
        int s1 = __builtin_amdgcn_readlane(srcs, e + 1);
        int s2 = __builtin_amdgcn_readlane(srcs, e + 2);
        int s3 = __builtin_amdgcn_readlane(srcs, e + 3);
        unsigned v0 = xb[(size_t)s0 * 64 + lane];
        unsigned v1 = xb[(size_t)s1 * 64 + lane];
        unsigned v2 = xb[(size_t)s2 * 64 + lane];
        unsigned v3 = xb[(size_t)s3 * 64 + lane];
        a0 += bf_lo(v0) + bf_lo(v1) + bf_lo(v2) + bf_lo(v3);
        a1 += bf_hi(v0) + bf_hi(v1) + bf_hi(v2) + bf_hi(v3);
    }
    for (; e < cnt; e++) {
        int s0 = __builtin_amdgcn_readlane(srcs, e);
        unsigned v0 = xb[(size_t)s0 * 64 + lane];
        a0 += bf_lo(v0); a1 += bf_hi(v0);
    }
    float scale = 1.0f / (float)max(d, 1);
    __builtin_nontemporal_store(pack_bf16x2(a0 * scale, a1 * scale),
                                &mo[(size_t)node * 64 + lane]);
}

// -------- merged fused GEMM (both node types): out = relu(normalize(mean@wl + b + x@wr))
__global__ __launch_bounds__(256) void gemm2_kernel(
    const unsigned* __restrict__ meanA, unsigned* __restrict__ xA,
    const short* __restrict__ BtA, const float* __restrict__ biasA,
    const unsigned* __restrict__ meanB, unsigned* __restrict__ xB,
    const short* __restrict__ BtB, const float* __restrict__ biasB,
    int nblocksA) {
    __shared__ __align__(16) short A_lds[128 * 72];
    __shared__ float rowsum[128][2];

    const int half = (blockIdx.x >= nblocksA) ? 1 : 0;
    const unsigned* meanb = half ? meanB : meanA;
    const unsigned* xdstb = half ? xB : xA;
    unsigned* outb = half ? xB : xA;
    const short* Bt = half ? BtB : BtA;
    const float* bias = half ? biasB : biasA;
    const int rb = (blockIdx.x - half * nblocksA) * 128;
    const int n_rows = NUM_I;

    const int tid  = threadIdx.x;
    const int lane = tid & 63;
    const int wv   = tid >> 6;
    const int wm   = wv >> 1;
    const int wn   = wv & 1;
    const int l15  = lane & 15;
    const int lq   = lane >> 4;

    floatx4 acc[4][4];
#pragma unroll
    for (int nt = 0; nt < 4; nt++) {
        float b = bias[wn * 64 + nt * 16 + l15];
#pragma unroll
        for (int mt = 0; mt < 4; mt++) acc[mt][nt] = (floatx4){b, b, b, b};
    }

    for (int kt = 0; kt < 4; kt++) {
        __syncthreads();
        const unsigned* srcbuf = (kt < 2) ? meanb : xdstb;
        const int kbase_u = (kt & 1) * 32;
#pragma unroll
        for (int j = 0; j < 4; j++) {
            int c = tid + j * 256;
            int row = c >> 3;
            int kc = (c & 7) * 8;
            int grow = rb + row;
            uint4 v = make_uint4(0u, 0u, 0u, 0u);
            if (grow < n_rows)
                v = *(const uint4*)(srcbuf + (size_t)grow * 64 + kbase_u + (kc >> 1));
            *(uint4*)&A_lds[row * 72 + kc] = v;
        }
        __syncthreads();

#pragma unroll
        for (int kk = 0; kk < 64; kk += 32) {
            shortx8 af[4], bfr[4];
#pragma unroll
            for (int mt = 0; mt < 4; mt++) {
                int row_l = wm * 64 + mt * 16 + l15;
                af[mt] = *(const shortx8*)&A_lds[row_l * 72 + kk + lq * 8];
            }
#pragma unroll
            for (int nt = 0; nt < 4; nt++) {
                int col = wn * 64 + nt * 16 + l15;
                int kg = kt * 64 + kk + lq * 8;
                bfr[nt] = *(const shortx8*)(Bt + col * 256 + kg);
            }
#pragma unroll
            for (int mt = 0; mt < 4; mt++)
#pragma unroll
                for (int nt = 0; nt < 4; nt++)
                    acc[mt][nt] = __builtin_amdgcn_mfma_f32_16x16x32_bf16(
                        af[mt], bfr[nt], acc[mt][nt], 0, 0, 0);
        }
    }

#pragma unroll
    for (int mt = 0; mt < 4; mt++) {
#pragma unroll
        for (int r = 0; r < 4; r++) {
            float p = 0.f;
#pragma unroll
            for (int nt = 0; nt < 4; nt++) { float x = acc[mt][nt][r]; p += x * x; }
            for (int o = 1; o < 16; o <<= 1) p += __shfl_xor(p, o);
            if (l15 == 0) rowsum[wm * 64 + mt * 16 + lq * 4 + r][wn] = p;
        }
    }
    __syncthreads();

#pragma unroll
    for (int mt = 0; mt < 4; mt++) {
#pragma unroll
        for (int r = 0; r < 4; r++) {
            int row_l = wm * 64 + mt * 16 + lq * 4 + r;
            int grow = rb + row_l;
            float s = rowsum[row_l][0] + rowsum[row_l][1];
            float inv = 1.f / fmaxf(sqrtf(s), 1e-12f);
#pragma unroll
            for (int nt = 0; nt < 4; nt++) {
                float v = fmaxf(acc[mt][nt][r] * inv, 0.f);
                float vnb = __shfl_xor(v, 1);
                if (grow < n_rows && (l15 & 1) == 0) {
                    int colpair = (wn * 64 + nt * 16 + l15) >> 1;
                    outb[(size_t)grow * 64 + colpair] = pack_bf16x2(v, vnb);
                }
            }
        }
    }
}

// -------- classifier: dot(xu2[src], xi2[dst]) per labeled edge, one wave per pair
__global__ __launch_bounds__(256) void classifier_kernel(
    const unsigned* __restrict__ xu, const unsigned* __restrict__ xi,
    const int* __restrict__ eli, float* __restrict__ out, int nL) {
    int wave = (blockIdx.x * blockDim.x + threadIdx.x) >> 6;
    int lane = threadIdx.x & 63;
    if (wave >= nL) return;
    int su = clampi(eli[wave], NUM_U);
    int di = clampi(eli[wave + nL], NUM_I);
    unsigned a = xu[(size_t)su * 64 + lane];
    unsigned b = xi[(size_t)di * 64 + lane];
    float p = bf_lo(a) * bf_lo(b) + bf_hi(a) * bf_hi(b);
    for (int o = 32; o; o >>= 1) p += __shfl_xor(p, o);
    if (lane == 0) __builtin_nontemporal_store(p, &out[wave]);
}

extern "C" void kernel_launch(void* const* d_in, const int* in_sizes, int n_in,
                              void* d_out, int out_size, void* d_ws, size_t ws_size,
                              hipStream_t stream) {
    const float* emb_user = (const float*)d_in[0];
    const float* emb_item = (const float*)d_in[1];
    const int* edge_rates = (const int*)d_in[2];
    const int* edge_rev   = (const int*)d_in[3];
    const int* eli        = (const int*)d_in[4];
    const float* b1_rates = (const float*)d_in[13];
    const float* b1_rev   = (const float*)d_in[14];
    const float* b2_rates = (const float*)d_in[15];
    const float* b2_rev   = (const float*)d_in[16];

    // workspace layout — ~142 MiB (bin_data regions alias meanI/meanU, dead before aggs)
    char* p = (char*)d_ws;
    auto alloc = [&](size_t bytes) -> void* {
        void* q = (void*)p;
        p += (bytes + 511) & ~(size_t)511;
        return q;
    };
    int* deg_rates    = (int*)alloc((size_t)NUM_I * 4);
    int* bucket_rates = (int*)alloc((size_t)NUM_I * CAP * 4);
    int* deg_rev      = (int*)alloc((size_t)NUM_U * 4);
    int* bucket_rev   = (int*)alloc((size_t)NUM_U * CAP * 4);
    unsigned* meanI = (unsigned*)alloc((size_t)NUM_I * 64 * 4);
    unsigned* meanU = (unsigned*)alloc((size_t)NUM_U * 64 * 4);
    unsigned* xi    = (unsigned*)alloc((size_t)NUM_I * 64 * 4);   // embI->xi1->xi2
    unsigned* xu    = (unsigned*)alloc((size_t)NUM_U * 64 * 4);   // embU->xu1->xu2
    short* Bt = (short*)alloc((size_t)4 * 32768 * 2);
    int* bin_cursor = (int*)alloc((size_t)2 * NBIN * 4);
    u64* bd0 = (u64*)meanI;   // 391*4608*8 = 14.4 MB <= 25.6 MB
    u64* bd1 = (u64*)meanU;

    const int gemmBlocks = (NUM_I + 127) / 128;                 // 782
    const int agg2Blocks = 2 * ((NUM_I + 3) / 4);               // 50000 (XCD-split grid)
    const int conv2Blocks = ((NUM_U + NUM_I) * 64 + 255) / 256;

    if (out_size > NL) {
        int tail = out_size - NL;
        zero_f32_kernel<<<(tail + 255) / 256, 256, 0, stream>>>((float*)d_out + NL, tail);
    }

    // ---- one-time prep (3 dispatches)
    transpose_w4_kernel<<<512, 256, 0, stream>>>(
        (const float*)d_in[5], (const float*)d_in[6],
        (const float*)d_in[7], (const float*)d_in[8],
        (const float*)d_in[9], (const float*)d_in[10],
        (const float*)d_in[11], (const float*)d_in[12], Bt, bin_cursor);
    conv2_kernel<<<conv2Blocks, 256, 0, stream>>>(emb_user, emb_item, xu, xi);
    partition2_kernel<<<2 * PB, 256, 0, stream>>>(edge_rates, edge_rev, bd0, bd1, bin_cursor);
    binscatter2_kernel<<<2 * NBIN, 256, 0, stream>>>(bd0, bd1, bin_cursor,
                                                     deg_rates, bucket_rates,
                                                     deg_rev, bucket_rev);

    // ---- layer 1 (aggs read pristine bf16 embs; in-place GEMMs)
    agg2_kernel<<<agg2Blocks, 256, 0, stream>>>(deg_rates, bucket_rates, xu, meanI,
                                                deg_rev, bucket_rev, xi, meanU);
    gemm2_kernel<<<2 * gemmBlocks, 256, 0, stream>>>(meanI, xi, Bt + 0 * 32768, b1_rates,
                                                     meanU, xu, Bt + 1 * 32768, b1_rev,
                                                     gemmBlocks);

    // ---- layer 2 (identical pointers: in-place buffers)
    agg2_kernel<<<agg2Blocks, 256, 0, stream>>>(deg_rates, bucket_rates, xu, meanI,
                                                deg_rev, bucket_rev, xi, meanU);
    gemm2_kernel<<<2 * gemmBlocks, 256, 0, stream>>>(meanI, xi, Bt + 2 * 32768, b2_rates,
                                                     meanU, xu, Bt + 3 * 32768, b2_rev,
                                                     gemmBlocks);

    classifier_kernel<<<(NL * 64 + 255) / 256, 256, 0, stream>>>(xu, xi, eli,
                                                                 (float*)d_out, NL);
}

// Round 6
// 630.633 us; speedup vs baseline: 1.1590x; 1.0015x over previous
//
#include <hip/hip_runtime.h>
#include <hip/hip_bf16.h>

#define NUM_U 100000
#define NUM_I 100000
#define NE    1600000
#define NL    100000
#define CAP   48
#define NBIN  391        // ceil(100000/256) coarse bins (dst>>8)
#define BINCAP 4608      // per-bin capacity; E[bin]=4096, +8 sigma
#define ROUND  4096      // edges per partition block
#define PB    391        // partition blocks per edge type = ceil(NE/ROUND)

typedef __attribute__((ext_vector_type(4))) float floatx4;
typedef __attribute__((ext_vector_type(8))) short shortx8;
typedef __attribute__((ext_vector_type(4))) unsigned uintx4;
typedef unsigned long long u64;

__device__ __forceinline__ float bf_lo(unsigned v) { return __uint_as_float(v << 16); }
__device__ __forceinline__ float bf_hi(unsigned v) { return __uint_as_float(v & 0xffff0000u); }

__device__ __forceinline__ unsigned pack_bf16x2(float lo, float hi) {
    __hip_bfloat16 l = __float2bfloat16(lo);
    __hip_bfloat16 h = __float2bfloat16(hi);
    unsigned short ul = *(unsigned short*)&l;
    unsigned short uh = *(unsigned short*)&h;
    return (unsigned)ul | ((unsigned)uh << 16);
}

__device__ __forceinline__ int clampi(int x, int hi) {
    return min(max(x, 0), hi - 1);
}

// -------- zero f32 tail of d_out beyond NL (poisoned 0xAA otherwise)
__global__ void zero_f32_kernel(float* __restrict__ p, int n) {
    int i = blockIdx.x * blockDim.x + threadIdx.x;
    if (i < n) p[i] = 0.0f;
}

// -------- both emb tables f32 [N][128] -> packed bf16x2, one dispatch
__global__ void conv2_kernel(const float* __restrict__ emb_u, const float* __restrict__ emb_i,
                             unsigned* __restrict__ xu, unsigned* __restrict__ xi) {
    int i = blockIdx.x * blockDim.x + threadIdx.x;
    const int nu = NUM_U * 64;
    if (i < nu) {
        float2 v = ((const float2*)emb_u)[i];
        xu[i] = pack_bf16x2(v.x, v.y);
    } else if (i < nu + NUM_I * 64) {
        int j = i - nu;
        float2 v = ((const float2*)emb_i)[j];
        xi[j] = pack_bf16x2(v.x, v.y);
    }
}

// -------- transpose the 4 f32 weight pairs into bf16 Bt[which][n][k]; also zeros bin_cursor
__global__ void transpose_w4_kernel(
    const float* __restrict__ w1l_rates, const float* __restrict__ w1r_rates,
    const float* __restrict__ w1l_rev,   const float* __restrict__ w1r_rev,
    const float* __restrict__ w2l_rates, const float* __restrict__ w2r_rates,
    const float* __restrict__ w2l_rev,   const float* __restrict__ w2r_rev,
    short* __restrict__ Bt, int* __restrict__ bin_cursor) {
    int idx = blockIdx.x * blockDim.x + threadIdx.x;  // 0 .. 4*32768-1
    if (idx < 2 * NBIN) bin_cursor[idx] = 0;
    int which = idx >> 15;
    int r = idx & 32767;
    int n = r >> 8;
    int k = r & 255;
    const float *wl, *wr;
    switch (which) {
        case 0:  wl = w1l_rates; wr = w1r_rates; break;
        case 1:  wl = w1l_rev;   wr = w1r_rev;   break;
        case 2:  wl = w2l_rates; wr = w2r_rates; break;
        default: wl = w2l_rev;   wr = w2r_rev;   break;
    }
    float v = (k < 128) ? wl[k * 128 + n] : wr[(k - 128) * 128 + n];
    __hip_bfloat16 b = __float2bfloat16(v);
    Bt[idx] = *(const short*)&b;
}

// -------- phase P (both edge types): block-local counting sort by dst>>8, coalesced
// runs into per-bin regions. bin_data entry = dst<<32|src.
__global__ __launch_bounds__(256) void partition2_kernel(
    const int* __restrict__ edges0, const int* __restrict__ edges1,
    u64* __restrict__ bd0, u64* __restrict__ bd1, int* __restrict__ cur) {
    __shared__ int hist[NBIN];
    __shared__ int prefix[NBIN];
    __shared__ int gbase[NBIN];
    __shared__ __align__(16) u64 sorted[ROUND];

    const int type = (blockIdx.x >= PB) ? 1 : 0;
    const int* edges = type ? edges1 : edges0;
    u64* bin_data = type ? bd1 : bd0;
    int* bin_cursor = cur + type * NBIN;
    const int blk  = blockIdx.x - type * PB;
    const int tid  = threadIdx.x;
    const int lane = tid & 63;
    const int wv   = tid >> 6;
    const int base = blk * ROUND;

    for (int k = tid; k < NBIN; k += 256) hist[k] = 0;
    __syncthreads();

    int mybin[16], myrank[16], mysrc[16], mydst[16];
#pragma unroll
    for (int r = 0; r < 16; r++) {
        int i = base + r * 256 + tid;
        mybin[r] = -1;
        if (i < NE) {
            mysrc[r] = clampi(edges[i], NUM_U);
            mydst[r] = clampi(edges[i + NE], NUM_I);
            mybin[r] = mydst[r] >> 8;
            myrank[r] = atomicAdd(&hist[mybin[r]], 1);
        }
    }
    __syncthreads();

    if (wv == 0) {   // exclusive scan of hist -> prefix
        int carry = 0;
        for (int c = 0; c < NBIN; c += 64) {
            int idx = c + lane;
            int h = (idx < NBIN) ? hist[idx] : 0;
            int v = h;
            for (int o = 1; o < 64; o <<= 1) {
                int t = __shfl_up(v, o);
                if (lane >= o) v += t;
            }
            if (idx < NBIN) prefix[idx] = v - h + carry;
            carry += __shfl(v, 63);
        }
    }
    __syncthreads();

#pragma unroll
    for (int r = 0; r < 16; r++) {
        if (mybin[r] >= 0) {
            int j = prefix[mybin[r]] + myrank[r];
            sorted[j] = ((u64)(unsigned)mydst[r] << 32) | (unsigned)mysrc[r];
        }
    }
    __syncthreads();

    for (int b = tid; b < NBIN; b += 256) {
        int cnt = hist[b];
        gbase[b] = (cnt > 0) ? atomicAdd(&bin_cursor[b], cnt) : 0;
    }
    __syncthreads();

    int total = min(ROUND, NE - base);
    for (int j = tid; j < total; j += 256) {
        u64 e = sorted[j];
        int b = (int)(e >> 40);
        int pos = gbase[b] + (j - prefix[b]);
        if (pos < BINCAP)
            bin_data[(size_t)b * BINCAP + pos] = e;
    }
}

// -------- phase Q (both edge types): one block per bin; LDS bucket build, coalesced out
__global__ __launch_bounds__(256) void binscatter2_kernel(
    const u64* __restrict__ bd0, const u64* __restrict__ bd1, const int* __restrict__ cur,
    int* __restrict__ deg0, int* __restrict__ bucket0,
    int* __restrict__ deg1, int* __restrict__ bucket1) {
    __shared__ int lbucket[256 * CAP];   // 48 KB
    __shared__ int ldeg[256];
    const int type = (blockIdx.x >= NBIN) ? 1 : 0;
    const int b = blockIdx.x - type * NBIN;
    const u64* bin_data = type ? bd1 : bd0;
    int* deg = type ? deg1 : deg0;
    int* bucket = type ? bucket1 : bucket0;
    const int tid = threadIdx.x;
    const int dstbase = b << 8;
    const int n_dst = NUM_I;

    ldeg[tid] = 0;
    __syncthreads();

    int count = min(cur[type * NBIN + b], BINCAP);
    for (int j = tid; j < count; j += 256) {
        u64 e = bin_data[(size_t)b * BINCAP + j];
        int src = (int)(unsigned)e;
        int dl = ((int)(e >> 32)) & 255;
        int pos = atomicAdd(&ldeg[dl], 1);
        if (pos < CAP) lbucket[dl * CAP + pos] = src;
    }
    __syncthreads();

    if (dstbase + tid < n_dst) deg[dstbase + tid] = ldeg[tid];
    int limit = min(256, n_dst - dstbase) * CAP;
    for (int k = tid; k < limit; k += 256)
        bucket[(size_t)dstbase * CAP + k] = lbucket[k];
}

// -------- aggregation v2 (both edge types): one wave = FOUR dst nodes, 16 lanes
// per node, dwordx4 gathers. Each gather instruction moves 1 KB (4 rows of 256 B)
// vs 256 B before, and a 4-edge unroll keeps ~4 KB in flight per wave — targets
// the latency x MLP regime identified by the occupancy-proportional throughput
// across R1-R3. Per-quarter src broadcast via __shfl (index uniform within each
// 16-lane quarter); short quarters are exec-masked per edge (no waste).
__global__ __launch_bounds__(256) void agg4_kernel(
    const int* __restrict__ degA, const int* __restrict__ bucketA,
    const unsigned* __restrict__ xA, unsigned* __restrict__ outA,
    const int* __restrict__ degB, const int* __restrict__ bucketB,
    const unsigned* __restrict__ xB, unsigned* __restrict__ outB) {
    const int w = (blockIdx.x * blockDim.x + threadIdx.x) >> 6;
    const int lane = threadIdx.x & 63;
    const int per = NUM_I / 4;   // 25000 waves per type (NUM_I == NUM_U, %4 == 0)
    const int* deg; const int* bucket; const unsigned* xb; unsigned* mo; int nb;
    if (w < per)          { deg = degA; bucket = bucketA; xb = xA; mo = outA; nb = w * 4; }
    else if (w < 2 * per) { deg = degB; bucket = bucketB; xb = xB; mo = outB; nb = (w - per) * 4; }
    else return;

    const int q = lane >> 4;      // quarter: which of the wave's 4 nodes
    const int j = lane & 15;      // lane-in-quarter: dims [8j, 8j+8)
    const int node = nb + q;

    // per-quarter edge list in 3 register chunks: sv_k at lane q*16+j holds
    // bucket[node*CAP + k*16 + j]
    int sv0 = __builtin_nontemporal_load(&bucket[(size_t)node * CAP + j]);
    int sv1 = __builtin_nontemporal_load(&bucket[(size_t)node * CAP + 16 + j]);
    int sv2 = __builtin_nontemporal_load(&bucket[(size_t)node * CAP + 32 + j]);
    int d   = deg[node];          // 4 consecutive ints per wave: one 16B line
    int cq  = min(d, CAP);        // uniform within quarter

    float a0 = 0.f, a1 = 0.f, a2 = 0.f, a3 = 0.f;
    float a4 = 0.f, a5 = 0.f, a6 = 0.f, a7 = 0.f;
    const unsigned* rowp = xb + ((size_t)j << 2);
    const int lq48 = lane & 48;

    for (int e = 0; e < CAP; e += 4) {
        if (!__any(e < cq)) break;
        int sve = (e < 16) ? sv0 : ((e < 32) ? sv1 : sv2);   // e..e+3 same chunk
        int s0 = __shfl(sve, lq48 + (e & 15) + 0);
        int s1 = __shfl(sve, lq48 + (e & 15) + 1);
        int s2 = __shfl(sve, lq48 + (e & 15) + 2);
        int s3 = __shfl(sve, lq48 + (e & 15) + 3);
        uintx4 v0 = (uintx4){0u, 0u, 0u, 0u};
        uintx4 v1 = (uintx4){0u, 0u, 0u, 0u};
        uintx4 v2 = (uintx4){0u, 0u, 0u, 0u};
        uintx4 v3 = (uintx4){0u, 0u, 0u, 0u};
        if (e + 0 < cq) v0 = *(const uintx4*)(rowp + (size_t)s0 * 64);
        if (e + 1 < cq) v1 = *(const uintx4*)(rowp + (size_t)s1 * 64);
        if (e + 2 < cq) v2 = *(const uintx4*)(rowp + (size_t)s2 * 64);
        if (e + 3 < cq) v3 = *(const uintx4*)(rowp + (size_t)s3 * 64);
        a0 += bf_lo(v0.x) + bf_lo(v1.x) + bf_lo(v2.x) + bf_lo(v3.x);
        a1 += bf_hi(v0.x) + bf_hi(v1.x) + bf_hi(v2.x) + bf_hi(v3.x);
        a2 += bf_lo(v0.y) + bf_lo(v1.y) + bf_lo(v2.y) + bf_lo(v3.y);
        a3 += bf_hi(v0.y) + bf_hi(v1.y) + bf_hi(v2.y) + bf_hi(v3.y);
        a4 += bf_lo(v0.z) + bf_lo(v1.z) + bf_lo(v2.z) + bf_lo(v3.z);
        a5 += bf_hi(v0.z) + bf_hi(v1.z) + bf_hi(v2.z) + bf_hi(v3.z);
        a6 += bf_lo(v0.w) + bf_lo(v1.w) + bf_lo(v2.w) + bf_lo(v3.w);
        a7 += bf_hi(v0.w) + bf_hi(v1.w) + bf_hi(v2.w) + bf_hi(v3.w);
    }

    float inv = 1.0f / (float)max(d, 1);
    uintx4 ov = (uintx4){pack_bf16x2(a0 * inv, a1 * inv),
                         pack_bf16x2(a2 * inv, a3 * inv),
                         pack_bf16x2(a4 * inv, a5 * inv),
                         pack_bf16x2(a6 * inv, a7 * inv)};
    __builtin_nontemporal_store(ov, (uintx4*)(mo + (size_t)node * 64 + ((size_t)j << 2)));
}

// -------- merged fused GEMM (both node types): out = relu(normalize(mean@wl + b + x@wr))
__global__ __launch_bounds__(256) void gemm2_kernel(
    const unsigned* __restrict__ meanA, unsigned* __restrict__ xA,
    const short* __restrict__ BtA, const float* __restrict__ biasA,
    const unsigned* __restrict__ meanB, unsigned* __restrict__ xB,
    const short* __restrict__ BtB, const float* __restrict__ biasB,
    int nblocksA) {
    __shared__ __align__(16) short A_lds[128 * 72];
    __shared__ float rowsum[128][2];

    const int half = (blockIdx.x >= nblocksA) ? 1 : 0;
    const unsigned* meanb = half ? meanB : meanA;
    const unsigned* xdstb = half ? xB : xA;
    unsigned* outb = half ? xB : xA;
    const short* Bt = half ? BtB : BtA;
    const float* bias = half ? biasB : biasA;
    const int rb = (blockIdx.x - half * nblocksA) * 128;
    const int n_rows = NUM_I;

    const int tid  = threadIdx.x;
    const int lane = tid & 63;
    const int wv   = tid >> 6;
    const int wm   = wv >> 1;
    const int wn   = wv & 1;
    const int l15  = lane & 15;
    const int lq   = lane >> 4;

    floatx4 acc[4][4];
#pragma unroll
    for (int nt = 0; nt < 4; nt++) {
        float b = bias[wn * 64 + nt * 16 + l15];
#pragma unroll
        for (int mt = 0; mt < 4; mt++) acc[mt][nt] = (floatx4){b, b, b, b};
    }

    for (int kt = 0; kt < 4; kt++) {
        __syncthreads();
        const unsigned* srcbuf = (kt < 2) ? meanb : xdstb;
        const int kbase_u = (kt & 1) * 32;
#pragma unroll
        for (int j = 0; j < 4; j++) {
            int c = tid + j * 256;
            int row = c >> 3;
            int kc = (c & 7) * 8;
            int grow = rb + row;
            uintx4 v = (uintx4){0u, 0u, 0u, 0u};
            if (grow < n_rows)
                v = *(const uintx4*)(srcbuf + (size_t)grow * 64 + kbase_u + (kc >> 1));
            *(uintx4*)&A_lds[row * 72 + kc] = v;
        }
        __syncthreads();

#pragma unroll
        for (int kk = 0; kk < 64; kk += 32) {
            shortx8 af[4], bfr[4];
#pragma unroll
            for (int mt = 0; mt < 4; mt++) {
                int row_l = wm * 64 + mt * 16 + l15;
                af[mt] = *(const shortx8*)&A_lds[row_l * 72 + kk + lq * 8];
            }
#pragma unroll
            for (int nt = 0; nt < 4; nt++) {
                int col = wn * 64 + nt * 16 + l15;
                int kg = kt * 64 + kk + lq * 8;
                bfr[nt] = *(const shortx8*)(Bt + col * 256 + kg);
            }
#pragma unroll
            for (int mt = 0; mt < 4; mt++)
#pragma unroll
                for (int nt = 0; nt < 4; nt++)
                    acc[mt][nt] = __builtin_amdgcn_mfma_f32_16x16x32_bf16(
                        af[mt], bfr[nt], acc[mt][nt], 0, 0, 0);
        }
    }

#pragma unroll
    for (int mt = 0; mt < 4; mt++) {
#pragma unroll
        for (int r = 0; r < 4; r++) {
            float p = 0.f;
#pragma unroll
            for (int nt = 0; nt < 4; nt++) { float x = acc[mt][nt][r]; p += x * x; }
            for (int o = 1; o < 16; o <<= 1) p += __shfl_xor(p, o);
            if (l15 == 0) rowsum[wm * 64 + mt * 16 + lq * 4 + r][wn] = p;
        }
    }
    __syncthreads();

#pragma unroll
    for (int mt = 0; mt < 4; mt++) {
#pragma unroll
        for (int r = 0; r < 4; r++) {
            int row_l = wm * 64 + mt * 16 + lq * 4 + r;
            int grow = rb + row_l;
            float s = rowsum[row_l][0] + rowsum[row_l][1];
            float inv = 1.f / fmaxf(sqrtf(s), 1e-12f);
#pragma unroll
            for (int nt = 0; nt < 4; nt++) {
                float v = fmaxf(acc[mt][nt][r] * inv, 0.f);
                float vnb = __shfl_xor(v, 1);
                if (grow < n_rows && (l15 & 1) == 0) {
                    int colpair = (wn * 64 + nt * 16 + l15) >> 1;
                    outb[(size_t)grow * 64 + colpair] = pack_bf16x2(v, vnb);
                }
            }
        }
    }
}

// -------- classifier: dot(xu2[src], xi2[dst]) per labeled edge, one wave per pair
__global__ __launch_bounds__(256) void classifier_kernel(
    const unsigned* __restrict__ xu, const unsigned* __restrict__ xi,
    const int* __restrict__ eli, float* __restrict__ out, int nL) {
    int wave = (blockIdx.x * blockDim.x + threadIdx.x) >> 6;
    int lane = threadIdx.x & 63;
    if (wave >= nL) return;
    int su = clampi(eli[wave], NUM_U);
    int di = clampi(eli[wave + nL], NUM_I);
    unsigned a = xu[(size_t)su * 64 + lane];
    unsigned b = xi[(size_t)di * 64 + lane];
    float p = bf_lo(a) * bf_lo(b) + bf_hi(a) * bf_hi(b);
    for (int o = 32; o; o >>= 1) p += __shfl_xor(p, o);
    if (lane == 0) __builtin_nontemporal_store(p, &out[wave]);
}

extern "C" void kernel_launch(void* const* d_in, const int* in_sizes, int n_in,
                              void* d_out, int out_size, void* d_ws, size_t ws_size,
                              hipStream_t stream) {
    const float* emb_user = (const float*)d_in[0];
    const float* emb_item = (const float*)d_in[1];
    const int* edge_rates = (const int*)d_in[2];
    const int* edge_rev   = (const int*)d_in[3];
    const int* eli        = (const int*)d_in[4];
    const float* b1_rates = (const float*)d_in[13];
    const float* b1_rev   = (const float*)d_in[14];
    const float* b2_rates = (const float*)d_in[15];
    const float* b2_rev   = (const float*)d_in[16];

    // workspace layout — ~142 MiB (bin_data regions alias meanI/meanU, dead before aggs)
    char* p = (char*)d_ws;
    auto alloc = [&](size_t bytes) -> void* {
        void* q = (void*)p;
        p += (bytes + 511) & ~(size_t)511;
        return q;
    };
    int* deg_rates    = (int*)alloc((size_t)NUM_I * 4);
    int* bucket_rates = (int*)alloc((size_t)NUM_I * CAP * 4);
    int* deg_rev      = (int*)alloc((size_t)NUM_U * 4);
    int* bucket_rev   = (int*)alloc((size_t)NUM_U * CAP * 4);
    unsigned* meanI = (unsigned*)alloc((size_t)NUM_I * 64 * 4);
    unsigned* meanU = (unsigned*)alloc((size_t)NUM_U * 64 * 4);
    unsigned* xi    = (unsigned*)alloc((size_t)NUM_I * 64 * 4);   // embI->xi1->xi2
    unsigned* xu    = (unsigned*)alloc((size_t)NUM_U * 64 * 4);   // embU->xu1->xu2
    short* Bt = (short*)alloc((size_t)4 * 32768 * 2);
    int* bin_cursor = (int*)alloc((size_t)2 * NBIN * 4);
    u64* bd0 = (u64*)meanI;   // 391*4608*8 = 14.4 MB <= 25.6 MB
    u64* bd1 = (u64*)meanU;

    const int gemmBlocks = (NUM_I + 127) / 128;                 // 782
    const int agg4Blocks = (2 * (NUM_I / 4) * 64) / 256;        // 12500
    const int conv2Blocks = ((NUM_U + NUM_I) * 64 + 255) / 256;

    if (out_size > NL) {
        int tail = out_size - NL;
        zero_f32_kernel<<<(tail + 255) / 256, 256, 0, stream>>>((float*)d_out + NL, tail);
    }

    // ---- one-time prep (3 dispatches)
    transpose_w4_kernel<<<512, 256, 0, stream>>>(
        (const float*)d_in[5], (const float*)d_in[6],
        (const float*)d_in[7], (const float*)d_in[8],
        (const float*)d_in[9], (const float*)d_in[10],
        (const float*)d_in[11], (const float*)d_in[12], Bt, bin_cursor);
    conv2_kernel<<<conv2Blocks, 256, 0, stream>>>(emb_user, emb_item, xu, xi);
    partition2_kernel<<<2 * PB, 256, 0, stream>>>(edge_rates, edge_rev, bd0, bd1, bin_cursor);
    binscatter2_kernel<<<2 * NBIN, 256, 0, stream>>>(bd0, bd1, bin_cursor,
                                                     deg_rates, bucket_rates,
                                                     deg_rev, bucket_rev);

    // ---- layer 1 (aggs read pristine bf16 embs; in-place GEMMs)
    agg4_kernel<<<agg4Blocks, 256, 0, stream>>>(deg_rates, bucket_rates, xu, meanI,
                                                deg_rev, bucket_rev, xi, meanU);
    gemm2_kernel<<<2 * gemmBlocks, 256, 0, stream>>>(meanI, xi, Bt + 0 * 32768, b1_rates,
                                                     meanU, xu, Bt + 1 * 32768, b1_rev,
                                                     gemmBlocks);

    // ---- layer 2 (identical pointers: in-place buffers)
    agg4_kernel<<<agg4Blocks, 256, 0, stream>>>(deg_rates, bucket_rates, xu, meanI,
                                                deg_rev, bucket_rev, xi, meanU);
    gemm2_kernel<<<2 * gemmBlocks, 256, 0, stream>>>(meanI, xi, Bt + 2 * 32768, b2_rates,
                                                     meanU, xu, Bt + 3 * 32768, b2_rev,
                                                     gemmBlocks);

    classifier_kernel<<<(NL * 64 + 255) / 256, 256, 0, stream>>>(xu, xi, eli,
                                                                 (float*)d_out, NL);
}